// Round 4
// baseline (244.624 us; speedup 1.0000x reference)
//
#include <hip/hip_runtime.h>
#include <hip/hip_bf16.h>
#include <math.h>

#define BROWS 4096
#define DIM   512
#define YEMB_E 2097152   // 4096*512, element offset of emb rows in Y
#define NPAIR 63

typedef float f32x4 __attribute__((ext_vector_type(4)));
typedef __bf16 bf16x8 __attribute__((ext_vector_type(8)));

// ---------------------------------------------------------------------------
// prep3: wave-per-row, no barriers. 8192 rows (low then emb), 4 rows/block.
// Lane holds 8 elems of the 512-elem row. Butterfly-reduce within the wave.
// Writes bf16 normalized row to Y, s=sum(y^2), r=sum(y) (fp32 y, pre-round).
// ---------------------------------------------------------------------------
__global__ __launch_bounds__(256) void prep3_kernel(
    const float* __restrict__ low, const float* __restrict__ emb,
    __hip_bfloat16* __restrict__ Y,
    float* __restrict__ s_l, float* __restrict__ r_l,
    float* __restrict__ s_e, float* __restrict__ r_e,
    float* __restrict__ out) {
  const int tid = threadIdx.x;
  const int lane = tid & 63, wid = tid >> 6;
  const int rid = blockIdx.x * 4 + wid;          // 0..8191
  if (blockIdx.x == 0 && tid == 0) out[0] = 0.f;

  const bool is_low = (rid < BROWS);
  const int row = is_low ? rid : rid - BROWS;
  const float* x = (is_low ? low : emb) + (size_t)row * DIM;

  const float4 v0 = ((const float4*)x)[lane * 2];
  const float4 v1 = ((const float4*)x)[lane * 2 + 1];

  float ss = v0.x * v0.x + v0.y * v0.y + v0.z * v0.z + v0.w * v0.w +
             v1.x * v1.x + v1.y * v1.y + v1.z * v1.z + v1.w * v1.w;
#pragma unroll
  for (int o = 1; o < 64; o <<= 1) ss += __shfl_xor(ss, o, 64);
  const float inv = 1.0f / fmaxf(sqrtf(ss), 1e-12f);

  float y[8] = {v0.x * inv, v0.y * inv, v0.z * inv, v0.w * inv,
                v1.x * inv, v1.y * inv, v1.z * inv, v1.w * inv};

  union { __hip_bfloat16 h[8]; uint4 u4; } pk;
  float sv = 0.f, rv = 0.f;
#pragma unroll
  for (int i = 0; i < 8; ++i) {
    pk.h[i] = __float2bfloat16(y[i]);
    sv += y[i] * y[i];
    rv += y[i];
  }
  ((uint4*)(Y + (size_t)rid * DIM))[lane] = pk.u4;

#pragma unroll
  for (int o = 1; o < 64; o <<= 1) {
    sv += __shfl_xor(sv, o, 64);
    rv += __shfl_xor(rv, o, 64);
  }
  if (lane == 0) {
    (is_low ? s_l : s_e)[row] = sv;
    (is_low ? r_l : r_e)[row] = rv;
  }
}

// ---------------------------------------------------------------------------
// Fused MFMA kernel, round 4: barrier-light structure.
// Block 256 thr (4 waves), tile 256 rows x 64 cols (63 pairs). Grid (65,16).
// B panel (64 cols x 256 K x 2 mats = 64 KB) LDS-resident per half-K phase:
//   staged once per phase via global_load_lds -> only 3 barriers total.
// A fragments stream global->VGPR directly (MFMA A layout == row-major
//   16-rows x 16B gather), pipelined by the compiler with fine vmcnt.
// LDS layout (elems): mat*16384 + kk*2048 + q8*512 + col*8  (kk: K32-step,
//   q8 = (k>>3)&3, col 0..63). Frag read = 256B contiguous per quad ->
//   conflict-free. Staging chunk c -> lds elem c*8 (wave-uniform base).
// C frag mapping (m89/m91): col(j) = lane&15, row(i) = (lane>>4)*4 + reg.
// ---------------------------------------------------------------------------
__global__ __launch_bounds__(256, 2) void fused_mfma_kernel(
    const __hip_bfloat16* __restrict__ Y,
    const float* __restrict__ s_l, const float* __restrict__ r_l,
    const float* __restrict__ s_e, const float* __restrict__ r_e,
    float* __restrict__ out) {
  __shared__ __align__(16) __hip_bfloat16 lds[32768];  // 64 KB
  __shared__ float sred[4];

  const int tid = threadIdx.x;
  const int lane = tid & 63;
  const int wid = tid >> 6;
  const int quad = lane >> 4;
  const int cpos = lane & 15;
  const int i0 = blockIdx.y * 256;
  const int c0 = blockIdx.x * NPAIR;

  // A-frag per-lane element offsets (fixed; phase/step added as immediate)
  int offa[2][4];
#pragma unroll
  for (int m = 0; m < 2; ++m)
#pragma unroll
    for (int u = 0; u < 4; ++u)
      offa[m][u] = m * YEMB_E + (i0 + 64 * wid + 16 * u + cpos) * DIM + quad * 8;

  f32x4 accl[4][4], acce[4][4];
#pragma unroll
  for (int u = 0; u < 4; ++u)
#pragma unroll
    for (int v = 0; v < 4; ++v) {
      accl[u][v] = (f32x4)(0.f);
      acce[u][v] = (f32x4)(0.f);
    }

  for (int p = 0; p < 2; ++p) {
    if (p) __syncthreads();  // all waves done reading LDS before restage
    const int pk = p * 256;  // K element offset of this phase

    // ---- stage B panel: 4096 chunks of 16B; thread t owns c = t + 256*s ----
#pragma unroll
    for (int s = 0; s < 16; ++s) {
      const int c = tid + 256 * s;
      const int mat = c >> 11;          // 0: low, 1: emb
      const int rem = c & 2047;
      const int kk = rem >> 8;          // 0..7  (K32 step)
      const int q8 = (rem >> 6) & 3;    // 8-elem group within K32
      const int col = rem & 63;
      const int goff = mat * YEMB_E + (c0 + col) * DIM + pk + kk * 32 + q8 * 8;
      __builtin_amdgcn_global_load_lds(
          (const __attribute__((address_space(1))) void*)(Y + goff),
          (__attribute__((address_space(3))) void*)(lds + 512 * wid + 2048 * s),
          16, 0, 0);
    }
    __syncthreads();

    // ---- 8 K32-steps, no barriers: A from global, B from LDS ----
#pragma unroll
    for (int kk = 0; kk < 8; ++kk) {
      bf16x8 a[2][4], b[2][4];
#pragma unroll
      for (int m = 0; m < 2; ++m)
#pragma unroll
        for (int u = 0; u < 4; ++u)
          a[m][u] = *(const bf16x8*)(Y + offa[m][u] + pk + kk * 32);
#pragma unroll
      for (int m = 0; m < 2; ++m)
#pragma unroll
        for (int v = 0; v < 4; ++v)
          b[m][v] = *(const bf16x8*)&lds[m * 16384 + kk * 2048 + quad * 512 +
                                         (16 * v + cpos) * 8];
#pragma unroll
      for (int u = 0; u < 4; ++u)
#pragma unroll
        for (int v = 0; v < 4; ++v) {
          accl[u][v] = __builtin_amdgcn_mfma_f32_16x16x32_bf16(
              a[0][u], b[0][v], accl[u][v], 0, 0, 0);
          acce[u][v] = __builtin_amdgcn_mfma_f32_16x16x32_bf16(
              a[1][u], b[1][v], acce[u][v], 0, 0, 0);
        }
    }
  }

  // ---- epilogue: distances + pair terms (verified in R2/R3) ----
  const float epsterm = (float)DIM * 1e-6f * 1e-6f;
  float sjl[4], rjl[4], sje[4], rje[4];
#pragma unroll
  for (int v = 0; v < 4; ++v) {
    const int j = c0 + 16 * v + cpos;  // <= 4095 always
    sjl[v] = s_l[j]; rjl[v] = r_l[j];
    sje[v] = s_e[j]; rje[v] = r_e[j];
  }

  float sum = 0.f;
#pragma unroll
  for (int u = 0; u < 4; ++u) {
    const int ibase = i0 + wid * 64 + 16 * u + quad * 4;
#pragma unroll
    for (int r = 0; r < 4; ++r) {
      const int i = ibase + r;
      const float sil = s_l[i], ril = r_l[i];
      const float sie = s_e[i], rie = r_e[i];
      float dl[4], de[4];
#pragma unroll
      for (int v = 0; v < 4; ++v) {
        const float sql = sil + sjl[v] - 2.f * accl[u][v][r] +
                          2e-6f * (ril - rjl[v]) + epsterm;
        dl[v] = sqrtf(fmaxf(sql, 0.f));
        const float sqe = sie + sje[v] - 2.f * acce[u][v][r] +
                          2e-6f * (rie - rje[v]) + epsterm;
        de[v] = sqrtf(fmaxf(sqe, 0.f));
      }
      const bool rowok = (i <= BROWS - 2);
      const int srcin = (lane & 48) | ((cpos + 1) & 15);
#pragma unroll
      for (int v = 0; v < 4; ++v) {
        float dl2 = __shfl(dl[v], srcin, 64);
        float de2 = __shfl(de[v], srcin, 64);
        if (v < 3) {
          const float dlb = __shfl(dl[v + 1], lane & 48, 64);
          const float deb = __shfl(de[v + 1], lane & 48, 64);
          if (cpos == 15) { dl2 = dlb; de2 = deb; }
        }
        const int pidx = 16 * v + cpos;
        const int j = c0 + pidx;
        if (rowok && pidx < NPAIR && j <= BROWS - 3) {
          const float aa = dl[v] - dl2;
          const float bb = de[v] - de2;
          const float coeff = (float)((aa > 0.f) - (aa < 0.f)) -
                              (float)((bb > 0.f) - (bb < 0.f));
          sum += coeff * (de2 - de[v]);
        }
      }
    }
  }

#pragma unroll
  for (int o = 32; o; o >>= 1) sum += __shfl_down(sum, o, 64);
  if (lane == 0) sred[wid] = sum;
  __syncthreads();
  if (tid == 0) {
    const float scale = 1.0f / ((float)(BROWS - 1) * (float)(BROWS - 2));
    atomicAdd(out, (sred[0] + sred[1] + sred[2] + sred[3]) * scale);
  }
}

// ===========================================================================
extern "C" void kernel_launch(void* const* d_in, const int* in_sizes, int n_in,
                              void* d_out, int out_size, void* d_ws,
                              size_t ws_size, hipStream_t stream) {
  const float* low = (const float*)d_in[0];
  const float* emb = (const float*)d_in[1];
  float* out = (float*)d_out;

  // ws: Y (2*4096*512 bf16 = 8 MB) then s_l, r_l, s_e, r_e (4096 f32 each)
  __hip_bfloat16* Y = (__hip_bfloat16*)d_ws;
  float* s_l = (float*)(Y + 2 * (size_t)BROWS * DIM);
  float* r_l = s_l + BROWS;
  float* s_e = r_l + BROWS;
  float* r_e = s_e + BROWS;

  prep3_kernel<<<2 * BROWS / 4, 256, 0, stream>>>(low, emb, Y, s_l, r_l, s_e, r_e, out);
  fused_mfma_kernel<<<dim3(65, 16), 256, 0, stream>>>(Y, s_l, r_l, s_e, r_e, out);
}

// Round 5
// 210.433 us; speedup vs baseline: 1.1625x; 1.1625x over previous
//
#include <hip/hip_runtime.h>
#include <hip/hip_bf16.h>
#include <math.h>

#define BROWS 4096
#define DIM   512
#define YEMB_E 2097152   // 4096*512, element offset of emb rows in Y
#define NPAIR 127        // pairs per block (block covers 128 cols)

typedef float f32x4 __attribute__((ext_vector_type(4)));
typedef __bf16 bf16x8 __attribute__((ext_vector_type(8)));

// ---------------------------------------------------------------------------
// prep3: wave-per-row, no barriers. 8192 rows (low then emb), 4 rows/block.
// ---------------------------------------------------------------------------
__global__ __launch_bounds__(256) void prep3_kernel(
    const float* __restrict__ low, const float* __restrict__ emb,
    __hip_bfloat16* __restrict__ Y,
    float* __restrict__ s_l, float* __restrict__ r_l,
    float* __restrict__ s_e, float* __restrict__ r_e,
    float* __restrict__ out) {
  const int tid = threadIdx.x;
  const int lane = tid & 63, wid = tid >> 6;
  const int rid = blockIdx.x * 4 + wid;          // 0..8191
  if (blockIdx.x == 0 && tid == 0) out[0] = 0.f;

  const bool is_low = (rid < BROWS);
  const int row = is_low ? rid : rid - BROWS;
  const float* x = (is_low ? low : emb) + (size_t)row * DIM;

  const float4 v0 = ((const float4*)x)[lane * 2];
  const float4 v1 = ((const float4*)x)[lane * 2 + 1];

  float ss = v0.x * v0.x + v0.y * v0.y + v0.z * v0.z + v0.w * v0.w +
             v1.x * v1.x + v1.y * v1.y + v1.z * v1.z + v1.w * v1.w;
#pragma unroll
  for (int o = 1; o < 64; o <<= 1) ss += __shfl_xor(ss, o, 64);
  const float inv = 1.0f / fmaxf(sqrtf(ss), 1e-12f);

  float y[8] = {v0.x * inv, v0.y * inv, v0.z * inv, v0.w * inv,
                v1.x * inv, v1.y * inv, v1.z * inv, v1.w * inv};

  union { __hip_bfloat16 h[8]; uint4 u4; } pk;
  float sv = 0.f, rv = 0.f;
#pragma unroll
  for (int i = 0; i < 8; ++i) {
    pk.h[i] = __float2bfloat16(y[i]);
    sv += y[i] * y[i];
    rv += y[i];
  }
  ((uint4*)(Y + (size_t)rid * DIM))[lane] = pk.u4;

#pragma unroll
  for (int o = 1; o < 64; o <<= 1) {
    sv += __shfl_xor(sv, o, 64);
    rv += __shfl_xor(rv, o, 64);
  }
  if (lane == 0) {
    (is_low ? s_l : s_e)[row] = sv;
    (is_low ? r_l : r_e)[row] = rv;
  }
}

// ---------------------------------------------------------------------------
// Fused MFMA kernel, round 5.
// Block 512 thr = 8 waves (wr = wid>>1 in 0..3, wc = wid&1).
// Block tile 256 rows x 128 cols; wave tile 64x64 per matrix.
// Staging: buffer_load_dwordx4 -> VGPR -> ds_write_b128 (bypasses the
//   ~10 B/cyc/CU global_load_lds path measured in R2/R3), double-buffered
//   LDS (2 x 48 KB), software prefetch one full iteration ahead,
//   ONE barrier per K32 iteration.
// LDS buffer layout (bf16 elems): Alow[256][32] @0, Aemb @8192,
//   Blow[128][32] @16384, Bemb @20480. Chunk c (16B) -> elem c*8.
// C frag mapping (m89/m91): col(j) = lane&15, row(i) = (lane>>4)*4 + reg.
// Cross-wave pair boundary (p=63) via small LDS handoff from wc=1 waves.
// ---------------------------------------------------------------------------
__global__ __launch_bounds__(512, 2) void fused_mfma_kernel(
    const __hip_bfloat16* __restrict__ Y,
    const float* __restrict__ s_l, const float* __restrict__ r_l,
    const float* __restrict__ s_e, const float* __restrict__ r_e,
    float* __restrict__ out) {
  __shared__ __align__(16) __hip_bfloat16 lds[2][24576];  // 96 KB
  __shared__ float hand[4][64][2];                        // 2 KB
  __shared__ float sred[8];

  const int tid = threadIdx.x;
  const int lane = tid & 63;
  const int wid = tid >> 6;        // 0..7
  const int wr = wid >> 1;         // 0..3 row-group
  const int wc = wid & 1;          // 0..1 col-group
  const int quad = lane >> 4;
  const int cpos = lane & 15;
  const int i0 = blockIdx.y * 256;
  const int c0 = blockIdx.x * NPAIR;

  // ---- staging: thread owns chunks c = tid + 512*s, s=0..5 ----
  int goff[6];   // element offset into Y (add k0 per iter)
  int loff[6];   // element offset into lds buffer
#pragma unroll
  for (int s = 0; s < 6; ++s) {
    const int c = tid + 512 * s;
    int o;
    if (c < 1024)       o = (i0 + (c >> 2)) * DIM;                          // Alow
    else if (c < 2048)  o = YEMB_E + (i0 + ((c - 1024) >> 2)) * DIM;        // Aemb
    else if (c < 2560)  o = min(c0 + ((c - 2048) >> 2), BROWS - 1) * DIM;   // Blow
    else                o = YEMB_E + min(c0 + ((c - 2560) >> 2), BROWS - 1) * DIM;
    goff[s] = o + (c & 3) * 8;
    loff[s] = c * 8;
  }

  f32x4 accl[4][4], acce[4][4];
#pragma unroll
  for (int u = 0; u < 4; ++u)
#pragma unroll
    for (int v = 0; v < 4; ++v) {
      accl[u][v] = (f32x4)(0.f);
      acce[u][v] = (f32x4)(0.f);
    }

  // frag LDS element offsets (within a buffer)
  int aoff[2][4], boff[2][4];
#pragma unroll
  for (int m = 0; m < 2; ++m) {
#pragma unroll
    for (int u = 0; u < 4; ++u)
      aoff[m][u] = m * 8192 + (64 * wr + 16 * u + cpos) * 32 + quad * 8;
#pragma unroll
    for (int v = 0; v < 4; ++v)
      boff[m][v] = 16384 + m * 4096 + (64 * wc + 16 * v + cpos) * 32 + quad * 8;
  }

  // ---- prologue: load it0, write buf0, load it1 ----
  uint4 rg[6];
#pragma unroll
  for (int s = 0; s < 6; ++s) rg[s] = *(const uint4*)(Y + goff[s]);
#pragma unroll
  for (int s = 0; s < 6; ++s) *(uint4*)&lds[0][loff[s]] = rg[s];
#pragma unroll
  for (int s = 0; s < 6; ++s) rg[s] = *(const uint4*)(Y + goff[s] + 32);
  __syncthreads();

  for (int it = 0; it < 16; ++it) {
    // stage it+1 into the other buffer (overlaps with compute below)
    if (it < 15) {
#pragma unroll
      for (int s = 0; s < 6; ++s) *(uint4*)&lds[(it + 1) & 1][loff[s]] = rg[s];
    }
    // prefetch it+2
    if (it < 14) {
      const int k0 = (it + 2) * 32;
#pragma unroll
      for (int s = 0; s < 6; ++s) rg[s] = *(const uint4*)(Y + goff[s] + k0);
    }
    // compute it
    {
      const __hip_bfloat16* buf = lds[it & 1];
      bf16x8 a[2][4], b[2][4];
#pragma unroll
      for (int m = 0; m < 2; ++m) {
#pragma unroll
        for (int u = 0; u < 4; ++u) a[m][u] = *(const bf16x8*)&buf[aoff[m][u]];
#pragma unroll
        for (int v = 0; v < 4; ++v) b[m][v] = *(const bf16x8*)&buf[boff[m][v]];
      }
#pragma unroll
      for (int u = 0; u < 4; ++u)
#pragma unroll
        for (int v = 0; v < 4; ++v) {
          accl[u][v] = __builtin_amdgcn_mfma_f32_16x16x32_bf16(
              a[0][u], b[0][v], accl[u][v], 0, 0, 0);
          acce[u][v] = __builtin_amdgcn_mfma_f32_16x16x32_bf16(
              a[1][u], b[1][v], acce[u][v], 0, 0, 0);
        }
    }
    __syncthreads();
  }

  // ---- epilogue ----
  const float epsterm = (float)DIM * 1e-6f * 1e-6f;

  // handoff: wc==1 waves publish their v=0 column (p would be 64) dl/de
  if (wc == 1 && cpos == 0) {
    const int j = min(c0 + 64, BROWS - 1);
    const float sjl = s_l[j], rjl = r_l[j];
    const float sje = s_e[j], rje = r_e[j];
#pragma unroll
    for (int u = 0; u < 4; ++u)
#pragma unroll
      for (int r = 0; r < 4; ++r) {
        const int i = i0 + 64 * wr + 16 * u + quad * 4 + r;
        const float sql = s_l[i] + sjl - 2.f * accl[u][0][r] +
                          2e-6f * (r_l[i] - rjl) + epsterm;
        const float sqe = s_e[i] + sje - 2.f * acce[u][0][r] +
                          2e-6f * (r_e[i] - rje) + epsterm;
        hand[wr][16 * u + 4 * quad + r][0] = sqrtf(fmaxf(sql, 0.f));
        hand[wr][16 * u + 4 * quad + r][1] = sqrtf(fmaxf(sqe, 0.f));
      }
  }
  __syncthreads();

  float sjl[4], rjl[4], sje[4], rje[4];
#pragma unroll
  for (int v = 0; v < 4; ++v) {
    const int j = min(c0 + 64 * wc + 16 * v + cpos, BROWS - 1);
    sjl[v] = s_l[j]; rjl[v] = r_l[j];
    sje[v] = s_e[j]; rje[v] = r_e[j];
  }

  float sum = 0.f;
#pragma unroll
  for (int u = 0; u < 4; ++u) {
    const int ibase = i0 + 64 * wr + 16 * u + quad * 4;
#pragma unroll
    for (int r = 0; r < 4; ++r) {
      const int i = ibase + r;
      const float sil = s_l[i], ril = r_l[i];
      const float sie = s_e[i], rie = r_e[i];
      float dl[4], de[4];
#pragma unroll
      for (int v = 0; v < 4; ++v) {
        const float sql = sil + sjl[v] - 2.f * accl[u][v][r] +
                          2e-6f * (ril - rjl[v]) + epsterm;
        dl[v] = sqrtf(fmaxf(sql, 0.f));
        const float sqe = sie + sje[v] - 2.f * acce[u][v][r] +
                          2e-6f * (rie - rje[v]) + epsterm;
        de[v] = sqrtf(fmaxf(sqe, 0.f));
      }
      const bool rowok = (i <= BROWS - 2);
      const int srcin = (lane & 48) | ((cpos + 1) & 15);
#pragma unroll
      for (int v = 0; v < 4; ++v) {
        float dl2 = __shfl(dl[v], srcin, 64);
        float de2 = __shfl(de[v], srcin, 64);
        if (v < 3) {
          const float dlb = __shfl(dl[v + 1], lane & 48, 64);
          const float deb = __shfl(de[v + 1], lane & 48, 64);
          if (cpos == 15) { dl2 = dlb; de2 = deb; }
        } else if (cpos == 15 && wc == 0) {
          dl2 = hand[wr][16 * u + 4 * quad + r][0];
          de2 = hand[wr][16 * u + 4 * quad + r][1];
        }
        const int p = 64 * wc + 16 * v + cpos;
        const int j = c0 + p;
        if (rowok && p < NPAIR && j <= BROWS - 3) {
          const float aa = dl[v] - dl2;
          const float bb = de[v] - de2;
          const float coeff = (float)((aa > 0.f) - (aa < 0.f)) -
                              (float)((bb > 0.f) - (bb < 0.f));
          sum += coeff * (de2 - de[v]);
        }
      }
    }
  }

#pragma unroll
  for (int o = 32; o; o >>= 1) sum += __shfl_down(sum, o, 64);
  if (lane == 0) sred[wid] = sum;
  __syncthreads();
  if (tid == 0) {
    const float scale = 1.0f / ((float)(BROWS - 1) * (float)(BROWS - 2));
    float t = 0.f;
#pragma unroll
    for (int w = 0; w < 8; ++w) t += sred[w];
    atomicAdd(out, t * scale);
  }
}

// ===========================================================================
extern "C" void kernel_launch(void* const* d_in, const int* in_sizes, int n_in,
                              void* d_out, int out_size, void* d_ws,
                              size_t ws_size, hipStream_t stream) {
  const float* low = (const float*)d_in[0];
  const float* emb = (const float*)d_in[1];
  float* out = (float*)d_out;

  // ws: Y (2*4096*512 bf16 = 8 MB) then s_l, r_l, s_e, r_e (4096 f32 each)
  __hip_bfloat16* Y = (__hip_bfloat16*)d_ws;
  float* s_l = (float*)(Y + 2 * (size_t)BROWS * DIM);
  float* r_l = s_l + BROWS;
  float* s_e = r_l + BROWS;
  float* r_e = s_e + BROWS;

  prep3_kernel<<<2 * BROWS / 4, 256, 0, stream>>>(low, emb, Y, s_l, r_l, s_e, r_e, out);
  // grid: ceil(4094 / 127) = 33 col-blocks, 16 row-blocks
  fused_mfma_kernel<<<dim3(33, 16), 512, 0, stream>>>(Y, s_l, r_l, s_e, r_e, out);
}

// Round 6
// 141.610 us; speedup vs baseline: 1.7274x; 1.4860x over previous
//
#include <hip/hip_runtime.h>
#include <hip/hip_bf16.h>
#include <math.h>

#define BROWS 4096
#define DIM   512
#define YEMB_E 2097152   // 4096*512, element offset of emb rows in Y
#define TSTRIDE 127      // tile stride (tiles are 128 wide, overlap by 1)

typedef float f32x4 __attribute__((ext_vector_type(4)));
typedef __bf16 bf16x8 __attribute__((ext_vector_type(8)));

// ---------------------------------------------------------------------------
// prep3: wave-per-row, no barriers. 8192 rows (low then emb), 4 rows/block.
// ---------------------------------------------------------------------------
__global__ __launch_bounds__(256) void prep3_kernel(
    const float* __restrict__ low, const float* __restrict__ emb,
    __hip_bfloat16* __restrict__ Y,
    float* __restrict__ s_l, float* __restrict__ r_l,
    float* __restrict__ s_e, float* __restrict__ r_e,
    float* __restrict__ out) {
  const int tid = threadIdx.x;
  const int lane = tid & 63, wid = tid >> 6;
  const int rid = blockIdx.x * 4 + wid;          // 0..8191
  if (blockIdx.x == 0 && tid == 0) out[0] = 0.f;

  const bool is_low = (rid < BROWS);
  const int row = is_low ? rid : rid - BROWS;
  const float* x = (is_low ? low : emb) + (size_t)row * DIM;

  const float4 v0 = ((const float4*)x)[lane * 2];
  const float4 v1 = ((const float4*)x)[lane * 2 + 1];

  float ss = v0.x * v0.x + v0.y * v0.y + v0.z * v0.z + v0.w * v0.w +
             v1.x * v1.x + v1.y * v1.y + v1.z * v1.z + v1.w * v1.w;
#pragma unroll
  for (int o = 1; o < 64; o <<= 1) ss += __shfl_xor(ss, o, 64);
  const float inv = 1.0f / fmaxf(sqrtf(ss), 1e-12f);

  float y[8] = {v0.x * inv, v0.y * inv, v0.z * inv, v0.w * inv,
                v1.x * inv, v1.y * inv, v1.z * inv, v1.w * inv};

  union { __hip_bfloat16 h[8]; uint4 u4; } pk;
  float sv = 0.f, rv = 0.f;
#pragma unroll
  for (int i = 0; i < 8; ++i) {
    pk.h[i] = __float2bfloat16(y[i]);
    sv += y[i] * y[i];
    rv += y[i];
  }
  ((uint4*)(Y + (size_t)rid * DIM))[lane] = pk.u4;

#pragma unroll
  for (int o = 1; o < 64; o <<= 1) {
    sv += __shfl_xor(sv, o, 64);
    rv += __shfl_xor(rv, o, 64);
  }
  if (lane == 0) {
    (is_low ? s_l : s_e)[row] = sv;
    (is_low ? r_l : r_e)[row] = rv;
  }
}

// ---------------------------------------------------------------------------
// Symmetric fused MFMA kernel, round 6.
// Grid 33x33; block (bc=bx, br=by) active iff br <= bc (561 blocks).
// Tile: rows r0=127*br..+127, cols c0=127*bc..+127 (128x128, 127-stride so
//   adjacent-pair neighbors stay in-tile). Ownership: i claimed if
//   (i mod 127) <= 126 within its tile => trow/tcol <= 126 filters.
// 4 waves in 2x2 (wr=wid>>1, wc=wid&1), wave tile 64x64 per matrix.
// K-loop: R3-proven structure — global_load_lds w=16, 32 KB/iter, BK=32,
//   single buffer, 2 barriers/iter, 32 MFMA/wave-iter.
// Epilogue: acc -> distances IN PLACE (accl/acce hold dl/de), then
//   direct pair terms (cols j,j+1) + transposed pair terms (rows, using
//   symmetry dist[i][j]=dist[j][i]); cross-wave boundaries via 1KB LDS
//   handoffs. Diagonal blocks (br==bc) emit direct only (full square).
// C frag mapping (m89/m91): col(j)=lane&15, row(i)=(lane>>4)*4+reg.
// ---------------------------------------------------------------------------
__global__ __launch_bounds__(256, 2) void fused_sym_kernel(
    const __hip_bfloat16* __restrict__ Y,
    const float* __restrict__ s_l, const float* __restrict__ r_l,
    const float* __restrict__ s_e, const float* __restrict__ r_e,
    float* __restrict__ out) {
  const int bc = blockIdx.x, br = blockIdx.y;
  if (br > bc) return;

  __shared__ __align__(16) __hip_bfloat16 lds[16384];  // 32 KB
  __shared__ float hand_d[2][64][2];   // [wr][local row][mat]: col-64 dists
  __shared__ float hand_t[2][64][2];   // [wc][local col][mat]: row-64 dists
  __shared__ float sred[4];

  const int tid = threadIdx.x;
  const int lane = tid & 63;
  const int wid = tid >> 6;
  const int wr = wid >> 1, wc = wid & 1;
  const int quad = lane >> 4, cpos = lane & 15;
  const int r0 = br * TSTRIDE, c0 = bc * TSTRIDE;

  // ---- staging offsets: 2048 x 16B chunks; thread owns c = tid + 256*s ----
  // segs: [0,512) Alow, [512,1024) Aemb, [1024,1536) Blow, [1536,2048) Bemb
  int goff[8];
#pragma unroll
  for (int s = 0; s < 8; ++s) {
    const int c = tid + 256 * s;
    int o;
    if (c < 512)        o = min(r0 + (c >> 2), BROWS - 1) * DIM;
    else if (c < 1024)  o = YEMB_E + min(r0 + ((c - 512) >> 2), BROWS - 1) * DIM;
    else if (c < 1536)  o = min(c0 + ((c - 1024) >> 2), BROWS - 1) * DIM;
    else                o = YEMB_E + min(c0 + ((c - 1536) >> 2), BROWS - 1) * DIM;
    goff[s] = o + (c & 3) * 8;
  }

  f32x4 accl[4][4], acce[4][4];
#pragma unroll
  for (int u = 0; u < 4; ++u)
#pragma unroll
    for (int v = 0; v < 4; ++v) {
      accl[u][v] = (f32x4)(0.f);
      acce[u][v] = (f32x4)(0.f);
    }

  int aoff[2][4], boff[2][4];
#pragma unroll
  for (int m = 0; m < 2; ++m) {
#pragma unroll
    for (int u = 0; u < 4; ++u)
      aoff[m][u] = m * 4096 + (64 * wr + 16 * u + cpos) * 32 + quad * 8;
#pragma unroll
    for (int v = 0; v < 4; ++v)
      boff[m][v] = 8192 + m * 4096 + (64 * wc + 16 * v + cpos) * 32 + quad * 8;
  }

  for (int k0 = 0; k0 < DIM; k0 += 32) {
#pragma unroll
    for (int s = 0; s < 8; ++s)
      __builtin_amdgcn_global_load_lds(
          (const __attribute__((address_space(1))) void*)(Y + goff[s] + k0),
          (__attribute__((address_space(3))) void*)(lds + (tid + 256 * s) * 8),
          16, 0, 0);
    __syncthreads();

    bf16x8 a[2][4], b[2][4];
#pragma unroll
    for (int m = 0; m < 2; ++m) {
#pragma unroll
      for (int u = 0; u < 4; ++u) a[m][u] = *(const bf16x8*)&lds[aoff[m][u]];
#pragma unroll
      for (int v = 0; v < 4; ++v) b[m][v] = *(const bf16x8*)&lds[boff[m][v]];
    }
#pragma unroll
    for (int u = 0; u < 4; ++u)
#pragma unroll
      for (int v = 0; v < 4; ++v) {
        accl[u][v] = __builtin_amdgcn_mfma_f32_16x16x32_bf16(
            a[0][u], b[0][v], accl[u][v], 0, 0, 0);
        acce[u][v] = __builtin_amdgcn_mfma_f32_16x16x32_bf16(
            a[1][u], b[1][v], acce[u][v], 0, 0, 0);
      }
    __syncthreads();
  }

  // ---- transform accumulators to distances in place ----
  const float epst = (float)DIM * 1e-6f * 1e-6f;
#pragma unroll
  for (int v = 0; v < 4; ++v) {
    const int j = min(c0 + 64 * wc + 16 * v + cpos, BROWS - 1);
    const float sjl = s_l[j], rjl = r_l[j];
    const float sje = s_e[j], rje = r_e[j];
#pragma unroll
    for (int u = 0; u < 4; ++u)
#pragma unroll
      for (int r = 0; r < 4; ++r) {
        const int i = min(r0 + 64 * wr + 16 * u + 4 * quad + r, BROWS - 1);
        const float sql = s_l[i] + sjl - 2.f * accl[u][v][r] +
                          2e-6f * (r_l[i] - rjl) + epst;
        accl[u][v][r] = sqrtf(fmaxf(sql, 0.f));
        const float sqe = s_e[i] + sje - 2.f * acce[u][v][r] +
                          2e-6f * (r_e[i] - rje) + epst;
        acce[u][v][r] = sqrtf(fmaxf(sqe, 0.f));
      }
  }

  // ---- publish cross-wave boundary values ----
  if (wc == 1 && cpos == 0) {   // tile col 64 (v=0,cpos=0), all 64 local rows
#pragma unroll
    for (int u = 0; u < 4; ++u)
#pragma unroll
      for (int r = 0; r < 4; ++r) {
        hand_d[wr][16 * u + 4 * quad + r][0] = accl[u][0][r];
        hand_d[wr][16 * u + 4 * quad + r][1] = acce[u][0][r];
      }
  }
  if (wr == 1 && quad == 0) {   // tile row 64 (u=0,quad=0,r=0), all 64 local cols
#pragma unroll
    for (int v = 0; v < 4; ++v) {
      hand_t[wc][16 * v + cpos][0] = accl[0][v][0];
      hand_t[wc][16 * v + cpos][1] = acce[0][v][0];
    }
  }
  __syncthreads();

  float sum = 0.f;

  // ---- pass 1: direct terms (i in rows, pair cols j,j+1) ----
  const int srcin = (lane & 48) | ((cpos + 1) & 15);
#pragma unroll
  for (int u = 0; u < 4; ++u)
#pragma unroll
    for (int r = 0; r < 4; ++r) {
      const int trow = 64 * wr + 16 * u + 4 * quad + r;
      const int i = r0 + trow;
      const bool rowok = (trow <= 126) && (i <= BROWS - 2);
#pragma unroll
      for (int v = 0; v < 4; ++v) {
        const float dl1 = accl[u][v][r], de1 = acce[u][v][r];
        float dl2 = __shfl(dl1, srcin, 64);
        float de2 = __shfl(de1, srcin, 64);
        if (v < 3) {
          const float dlb = __shfl(accl[u][v + 1][r], lane & 48, 64);
          const float deb = __shfl(acce[u][v + 1][r], lane & 48, 64);
          if (cpos == 15) { dl2 = dlb; de2 = deb; }
        } else if (cpos == 15 && wc == 0) {
          dl2 = hand_d[wr][16 * u + 4 * quad + r][0];
          de2 = hand_d[wr][16 * u + 4 * quad + r][1];
        }
        const int tcol = 64 * wc + 16 * v + cpos;
        const int j = c0 + tcol;
        if (rowok && tcol <= 126 && j <= BROWS - 3) {
          const float aa = dl1 - dl2, bb = de1 - de2;
          const float coeff = (float)((aa > 0.f) - (aa < 0.f)) -
                              (float)((bb > 0.f) - (bb < 0.f));
          sum += coeff * (de2 - de1);
        }
      }
    }

  // ---- pass 2: transposed terms (i in cols, pair rows j,j+1), off-diag only ----
  if (br != bc) {
#pragma unroll
    for (int u = 0; u < 4; ++u)
#pragma unroll
      for (int v = 0; v < 4; ++v) {
        const int tcol = 64 * wc + 16 * v + cpos;
        const int ii = c0 + tcol;
        const bool colok = (tcol <= 126) && (ii <= BROWS - 2);
#pragma unroll
        for (int r = 0; r < 3; ++r) {
          const int trow = 64 * wr + 16 * u + 4 * quad + r;
          const int jj = r0 + trow;
          if (colok && trow <= 126 && jj <= BROWS - 3) {
            const float aa = accl[u][v][r] - accl[u][v][r + 1];
            const float bb = acce[u][v][r] - acce[u][v][r + 1];
            const float coeff = (float)((aa > 0.f) - (aa < 0.f)) -
                                (float)((bb > 0.f) - (bb < 0.f));
            sum += coeff * (acce[u][v][r + 1] - acce[u][v][r]);
          }
        }
        {  // r == 3 boundary: next row lives in another quad/u/wave
          const int trow = 64 * wr + 16 * u + 4 * quad + 3;
          const int jj = r0 + trow;
          const float dlq = __shfl(accl[u][v][0], (lane + 16) & 63, 64);
          const float deq = __shfl(acce[u][v][0], (lane + 16) & 63, 64);
          const float dlu = (u < 3) ? __shfl(accl[(u < 3 ? u + 1 : u)][v][0], cpos, 64) : 0.f;
          const float deu = (u < 3) ? __shfl(acce[(u < 3 ? u + 1 : u)][v][0], cpos, 64) : 0.f;
          float dl2, de2;
          if (quad < 3)      { dl2 = dlq; de2 = deq; }
          else if (u < 3)    { dl2 = dlu; de2 = deu; }
          else               { dl2 = hand_t[wc][16 * v + cpos][0];
                               de2 = hand_t[wc][16 * v + cpos][1]; }
          if (colok && trow <= 126 && jj <= BROWS - 3) {
            const float dl1 = accl[u][v][3], de1 = acce[u][v][3];
            const float aa = dl1 - dl2, bb = de1 - de2;
            const float coeff = (float)((aa > 0.f) - (aa < 0.f)) -
                                (float)((bb > 0.f) - (bb < 0.f));
            sum += coeff * (de2 - de1);
          }
        }
      }
  }

  // ---- reduce + atomic ----
#pragma unroll
  for (int o = 32; o; o >>= 1) sum += __shfl_down(sum, o, 64);
  if (lane == 0) sred[wid] = sum;
  __syncthreads();
  if (tid == 0) {
    const float scale = 1.0f / ((float)(BROWS - 1) * (float)(BROWS - 2));
    atomicAdd(out, (sred[0] + sred[1] + sred[2] + sred[3]) * scale);
  }
}

// ===========================================================================
extern "C" void kernel_launch(void* const* d_in, const int* in_sizes, int n_in,
                              void* d_out, int out_size, void* d_ws,
                              size_t ws_size, hipStream_t stream) {
  const float* low = (const float*)d_in[0];
  const float* emb = (const float*)d_in[1];
  float* out = (float*)d_out;

  // ws: Y (2*4096*512 bf16 = 8 MB) then s_l, r_l, s_e, r_e (4096 f32 each)
  __hip_bfloat16* Y = (__hip_bfloat16*)d_ws;
  float* s_l = (float*)(Y + 2 * (size_t)BROWS * DIM);
  float* r_l = s_l + BROWS;
  float* s_e = r_l + BROWS;
  float* r_e = s_e + BROWS;

  prep3_kernel<<<2 * BROWS / 4, 256, 0, stream>>>(low, emb, Y, s_l, r_l, s_e, r_e, out);
  fused_sym_kernel<<<dim3(33, 33), 256, 0, stream>>>(Y, s_l, r_l, s_e, r_e, out);
}